// Round 1
// baseline (149.114 us; speedup 1.0000x reference)
//
#include <hip/hip_runtime.h>
#include <stdint.h>

// RBF kernel regression: out = (exp(-gamma*d2(Xq,Xt)) ) @ alpha
// Factored: out[m] = ea[m] * sum_n w[n] * 2^( S[m][n] ),
//   S = (2*gamma*log2e * Xq) . Xt^T   (bf16 MFMA, fp32 acc)
//   w[n] = alpha[n]*exp(-gamma*|Xt_n|^2), ea[m] = exp(-gamma*|Xq_m|^2)

#define MM 8192
#define NN 8192
#define DD 256
#define GAMMA (1.0f/256.0f)
#define LOG2E 1.44269504088896340736f
#define SCALE_A (2.0f*GAMMA*LOG2E)

#define BM 128
#define BN 128
#define NSPLIT 8
#define NPB (NN/NSPLIT)        // 1024 cols per block
#define NSTAGES ((NPB/BN)*4)   // 4 k-stages (BK=64) per 128-col tile -> 32

typedef __bf16 bf16x8 __attribute__((ext_vector_type(8)));
typedef float  f32x4  __attribute__((ext_vector_type(4)));

// ws layout: [0,4MB) A bf16 (scaled, row-major 8192x256)
//            [4MB,8MB) B staged: [s:4][n:8192][g':8] granules of 16B,
//                      granule g' holds global granule g = g' ^ (n&7)  (LDS-bank swizzle)
//            [8MB, +32KB) w[n] fp32 ; [8MB+32KB, +32KB) ea[m] fp32
#define A_OFF  ((size_t)0)
#define B_OFF  ((size_t)4 << 20)
#define W_OFF  ((size_t)8 << 20)
#define EA_OFF (((size_t)8 << 20) + 32768)

__device__ __forceinline__ unsigned short f2bf(float f) {  // RNE f32->bf16
  union { float f; uint32_t u; } x; x.f = f;
  uint32_t u = x.u;
  u += 0x7FFFu + ((u >> 16) & 1u);
  return (unsigned short)(u >> 16);
}

__device__ __forceinline__ void async_ld16(void* lds, const void* g) {
  // dest = wave-uniform lds base + lane*16 (HW behavior)
  __builtin_amdgcn_global_load_lds(
      (const __attribute__((address_space(1))) uint32_t*)g,
      (__attribute__((address_space(3))) uint32_t*)lds, 16, 0, 0);
}

__global__ __launch_bounds__(256) void prep_kernel(
    const float* __restrict__ Xq, const float* __restrict__ Xt,
    const float* __restrict__ alpha, float* __restrict__ out,
    unsigned short* __restrict__ Aq, char* __restrict__ Bst,
    float* __restrict__ w, float* __restrict__ ea)
{
  const int lane = threadIdx.x & 63;
  const int row  = (blockIdx.x << 2) + (threadIdx.x >> 6);  // one wave per row
  if (row < MM) {
    const float4 v = *(const float4*)(Xq + (size_t)row * DD + lane * 4);
    float ss = v.x*v.x + v.y*v.y + v.z*v.z + v.w*v.w;
#pragma unroll
    for (int off = 32; off; off >>= 1) ss += __shfl_xor(ss, off, 64);
    ushort4 p;
    p.x = f2bf(v.x * SCALE_A); p.y = f2bf(v.y * SCALE_A);
    p.z = f2bf(v.z * SCALE_A); p.w = f2bf(v.w * SCALE_A);
    *(ushort4*)(Aq + (size_t)row * DD + lane * 4) = p;
    if (lane == 0) { ea[row] = __expf(-GAMMA * ss); out[row] = 0.0f; }
  } else {
    const int n = row - MM;
    const float4 v = *(const float4*)(Xt + (size_t)n * DD + lane * 4);
    float ss = v.x*v.x + v.y*v.y + v.z*v.z + v.w*v.w;
#pragma unroll
    for (int off = 32; off; off >>= 1) ss += __shfl_xor(ss, off, 64);
    ushort4 p;
    p.x = f2bf(v.x); p.y = f2bf(v.y); p.z = f2bf(v.z); p.w = f2bf(v.w);
    // lane holds k = 4*lane..4*lane+3 -> k-chunk s = lane>>4, granule g = lane>>1
    const int s  = lane >> 4;
    const int gp = ((lane >> 1) & 7) ^ (n & 7);
    const size_t addr = (((size_t)(s * NN + n) * 8 + gp) << 4) + (size_t)(lane & 1) * 8;
    *(uint2*)(Bst + addr) =
        make_uint2((uint32_t)p.x | ((uint32_t)p.y << 16),
                   (uint32_t)p.z | ((uint32_t)p.w << 16));
    if (lane == 0) w[n] = alpha[n] * __expf(-GAMMA * ss);
  }
}

__global__ __launch_bounds__(256, 2) void rbf_main(
    const unsigned short* __restrict__ Aq, const char* __restrict__ Bst,
    const float* __restrict__ w, const float* __restrict__ ea,
    float* __restrict__ out)
{
  __shared__ char lds[2 * 16384];  // double-buffered B stage: 128 rows x 128 B
  const int tid  = threadIdx.x;
  const int wave = tid >> 6, lane = tid & 63;
  const int quad = lane >> 4, l16 = lane & 15;
  const int mblk   = blockIdx.y * BM;
  const int nbase0 = blockIdx.x * NPB;

  // A fragments register-resident for full K=256:
  // A[m=lane&15][k=quad*8+j] per 16x16x32 tile -> 8 contiguous bf16 per lane
  bf16x8 afrag[2][8];
#pragma unroll
  for (int rt = 0; rt < 2; ++rt)
#pragma unroll
    for (int kc = 0; kc < 8; ++kc) {
      union { uint4 u; bf16x8 v; } cv;
      cv.u = *(const uint4*)(Aq + (size_t)(mblk + wave * 32 + rt * 16 + l16) * DD
                                 + kc * 32 + quad * 8);
      afrag[rt][kc] = cv.v;
    }

  const f32x4 fzero = {0.f, 0.f, 0.f, 0.f};
  f32x4 acc[2][8];
#pragma unroll
  for (int rt = 0; rt < 2; ++rt)
#pragma unroll
    for (int ct = 0; ct < 8; ++ct) acc[rt][ct] = fzero;
  float outacc[2][4] = {{0.f,0.f,0.f,0.f},{0.f,0.f,0.f,0.f}};

  auto issue = [&](int st) {
    const int ntile = st >> 2, s = st & 3;
    const char* g = Bst + ((size_t)(s * NN + nbase0 + ntile * BN + wave * 32) << 7)
                        + (size_t)lane * 16;
    char* l = lds + (st & 1) * 16384 + wave * 32 * 128;  // wave-uniform
#pragma unroll
    for (int j = 0; j < 4; ++j) async_ld16(l + j * 1024, g + j * 1024);
  };

  issue(0);
  for (int st = 0; st < NSTAGES; ++st) {
    __syncthreads();                       // buf[st&1] staged; buf[(st+1)&1] free
    if (st + 1 < NSTAGES) issue(st + 1);
    const char* buf = lds + (st & 1) * 16384;
#pragma unroll
    for (int kcL = 0; kcL < 2; ++kcL) {
      const int kc = (st & 3) * 2 + kcL;
#pragma unroll
      for (int ct = 0; ct < 8; ++ct) {
        // B[n=lane&15][k contiguous 8]; row r=ct*16+l16, granule g=kcL*4+quad,
        // stored at g' = g ^ (r&7)  -> 2-way-max bank aliasing (free)
        const int gp = (kcL * 4 + quad) ^ (l16 & 7);
        union { uint4 u; bf16x8 v; } cv;
        cv.u = *(const uint4*)(buf + (ct * 16 + l16) * 128 + gp * 16);
        acc[0][ct] = __builtin_amdgcn_mfma_f32_16x16x32_bf16(afrag[0][kc], cv.v, acc[0][ct], 0, 0, 0);
        acc[1][ct] = __builtin_amdgcn_mfma_f32_16x16x32_bf16(afrag[1][kc], cv.v, acc[1][ct], 0, 0, 0);
      }
    }
    if ((st & 3) == 3) {  // epilogue for finished 128-col tile: C/D row=quad*4+reg, col=l16
      const int nb = nbase0 + (st >> 2) * BN;
#pragma unroll
      for (int ct = 0; ct < 8; ++ct) {
        const float wv = w[nb + ct * 16 + l16];
#pragma unroll
        for (int rt = 0; rt < 2; ++rt) {
          f32x4 a = acc[rt][ct];
          outacc[rt][0] += wv * __ocml_exp2_f32(a[0]);
          outacc[rt][1] += wv * __ocml_exp2_f32(a[1]);
          outacc[rt][2] += wv * __ocml_exp2_f32(a[2]);
          outacc[rt][3] += wv * __ocml_exp2_f32(a[3]);
          acc[rt][ct] = fzero;
        }
      }
    }
  }

  // reduce over the 16 columns held across l16 within each quad, then atomic per row
#pragma unroll
  for (int rt = 0; rt < 2; ++rt)
#pragma unroll
    for (int i = 0; i < 4; ++i) {
      float v = outacc[rt][i];
      v += __shfl_xor(v, 1, 64);
      v += __shfl_xor(v, 2, 64);
      v += __shfl_xor(v, 4, 64);
      v += __shfl_xor(v, 8, 64);
      if (l16 == 0) {
        const int row = mblk + wave * 32 + rt * 16 + quad * 4 + i;
        atomicAdd(out + row, ea[row] * v);
      }
    }
}

extern "C" void kernel_launch(void* const* d_in, const int* in_sizes, int n_in,
                              void* d_out, int out_size, void* d_ws, size_t ws_size,
                              hipStream_t stream) {
  const float* Xq    = (const float*)d_in[0];
  const float* Xt    = (const float*)d_in[1];
  const float* alpha = (const float*)d_in[2];
  float* out = (float*)d_out;
  char*  ws  = (char*)d_ws;

  unsigned short* Aq = (unsigned short*)(ws + A_OFF);
  char*  Bst = ws + B_OFF;
  float* w   = (float*)(ws + W_OFF);
  float* ea  = (float*)(ws + EA_OFF);

  hipLaunchKernelGGL(prep_kernel, dim3((MM + NN) / 4), dim3(256), 0, stream,
                     Xq, Xt, alpha, out, Aq, Bst, w, ea);
  hipLaunchKernelGGL(rbf_main, dim3(NSPLIT, MM / BM), dim3(256), 0, stream,
                     Aq, Bst, w, ea, out);
}

// Round 2
// 142.030 us; speedup vs baseline: 1.0499x; 1.0499x over previous
//
#include <hip/hip_runtime.h>
#include <stdint.h>

// RBF kernel regression: out = (exp(-gamma*d2(Xq,Xt)) ) @ alpha
// Factored: out[m] = ea[m] * sum_n w[n] * 2^( S[m][n] ),
//   S = (2*gamma*log2e * Xq) . Xt^T   (bf16 MFMA, fp32 acc)
//   w[n] = alpha[n]*exp(-gamma*|Xt_n|^2), ea[m] = exp(-gamma*|Xq_m|^2)

#define MM 8192
#define NN 8192
#define DD 256
#define GAMMA (1.0f/256.0f)
#define LOG2E 1.44269504088896340736f
#define SCALE_A (2.0f*GAMMA*LOG2E)
#define NEG_G_LOG2E (-GAMMA*LOG2E)

#define BM 128
#define BN 128
#define NSPLIT 16              // 1024 blocks = 4 blocks/CU (R2: was 8 -> 2/CU, 21% occ)
#define NPB (NN/NSPLIT)        // 512 cols per block
#define NSTAGES ((NPB/BN)*4)   // 4 k-stages (BK=64) per 128-col tile -> 16

typedef __bf16 bf16x8 __attribute__((ext_vector_type(8)));
typedef float  f32x4  __attribute__((ext_vector_type(4)));

// ws layout: [0,4MB) A bf16 (scaled, row-major 8192x256)
//            [4MB,8MB) B staged: [s:4][n:8192][g':8] granules of 16B,
//                      granule g' holds global granule g = g' ^ (n&7)  (LDS-bank swizzle)
//            [8MB, +32KB) w[n] fp32 ; [8MB+32KB, +32KB) ea[m] fp32
#define A_OFF  ((size_t)0)
#define B_OFF  ((size_t)4 << 20)
#define W_OFF  ((size_t)8 << 20)
#define EA_OFF (((size_t)8 << 20) + 32768)

__device__ __forceinline__ unsigned short f2bf(float f) {  // RNE f32->bf16
  union { float f; uint32_t u; } x; x.f = f;
  uint32_t u = x.u;
  u += 0x7FFFu + ((u >> 16) & 1u);
  return (unsigned short)(u >> 16);
}

__device__ __forceinline__ void async_ld16(void* lds, const void* g) {
  // dest = wave-uniform lds base + lane*16 (HW behavior)
  __builtin_amdgcn_global_load_lds(
      (const __attribute__((address_space(1))) uint32_t*)g,
      (__attribute__((address_space(3))) uint32_t*)lds, 16, 0, 0);
}

__global__ __launch_bounds__(256) void prep_kernel(
    const float* __restrict__ Xq, const float* __restrict__ Xt,
    const float* __restrict__ alpha, float* __restrict__ out,
    unsigned short* __restrict__ Aq, char* __restrict__ Bst,
    float* __restrict__ w, float* __restrict__ ea)
{
  const int lane = threadIdx.x & 63;
  const int row  = (blockIdx.x << 2) + (threadIdx.x >> 6);  // one wave per row
  if (row < MM) {
    const float4 v = *(const float4*)(Xq + (size_t)row * DD + lane * 4);
    float ss = v.x*v.x + v.y*v.y + v.z*v.z + v.w*v.w;
#pragma unroll
    for (int off = 32; off; off >>= 1) ss += __shfl_xor(ss, off, 64);
    ushort4 p;
    p.x = f2bf(v.x * SCALE_A); p.y = f2bf(v.y * SCALE_A);
    p.z = f2bf(v.z * SCALE_A); p.w = f2bf(v.w * SCALE_A);
    *(ushort4*)(Aq + (size_t)row * DD + lane * 4) = p;
    if (lane == 0) { ea[row] = __builtin_amdgcn_exp2f(NEG_G_LOG2E * ss); out[row] = 0.0f; }
  } else {
    const int n = row - MM;
    const float4 v = *(const float4*)(Xt + (size_t)n * DD + lane * 4);
    float ss = v.x*v.x + v.y*v.y + v.z*v.z + v.w*v.w;
#pragma unroll
    for (int off = 32; off; off >>= 1) ss += __shfl_xor(ss, off, 64);
    ushort4 p;
    p.x = f2bf(v.x); p.y = f2bf(v.y); p.z = f2bf(v.z); p.w = f2bf(v.w);
    // lane holds k = 4*lane..4*lane+3 -> k-chunk s = lane>>4, granule g = lane>>1
    const int s  = lane >> 4;
    const int gp = ((lane >> 1) & 7) ^ (n & 7);
    const size_t addr = (((size_t)(s * NN + n) * 8 + gp) << 4) + (size_t)(lane & 1) * 8;
    *(uint2*)(Bst + addr) =
        make_uint2((uint32_t)p.x | ((uint32_t)p.y << 16),
                   (uint32_t)p.z | ((uint32_t)p.w << 16));
    if (lane == 0) w[n] = alpha[n] * __builtin_amdgcn_exp2f(NEG_G_LOG2E * ss);
  }
}

__global__ __launch_bounds__(256, 4) void rbf_main(
    const unsigned short* __restrict__ Aq, const char* __restrict__ Bst,
    const float* __restrict__ w, const float* __restrict__ ea,
    float* __restrict__ out)
{
  __shared__ char lds[2 * 16384];  // double-buffered B stage: 128 rows x 128 B
  const int tid  = threadIdx.x;
  const int wave = tid >> 6, lane = tid & 63;
  const int quad = lane >> 4, l16 = lane & 15;
  const int mblk   = blockIdx.y * BM;
  const int nbase0 = blockIdx.x * NPB;

  // A fragments register-resident for full K=256:
  // A[m=lane&15][k=quad*8+j] per 16x16x32 tile -> 8 contiguous bf16 per lane
  bf16x8 afrag[2][8];
#pragma unroll
  for (int rt = 0; rt < 2; ++rt)
#pragma unroll
    for (int kc = 0; kc < 8; ++kc) {
      union { uint4 u; bf16x8 v; } cv;
      cv.u = *(const uint4*)(Aq + (size_t)(mblk + wave * 32 + rt * 16 + l16) * DD
                                 + kc * 32 + quad * 8);
      afrag[rt][kc] = cv.v;
    }

  const f32x4 fzero = {0.f, 0.f, 0.f, 0.f};
  f32x4 acc[2][8];
#pragma unroll
  for (int rt = 0; rt < 2; ++rt)
#pragma unroll
    for (int ct = 0; ct < 8; ++ct) acc[rt][ct] = fzero;
  float outacc[2][4] = {{0.f,0.f,0.f,0.f},{0.f,0.f,0.f,0.f}};

  auto issue = [&](int st) {
    const int ntile = st >> 2, s = st & 3;
    const char* g = Bst + ((size_t)(s * NN + nbase0 + ntile * BN + wave * 32) << 7)
                        + (size_t)lane * 16;
    char* l = lds + (st & 1) * 16384 + wave * 32 * 128;  // wave-uniform
#pragma unroll
    for (int j = 0; j < 4; ++j) async_ld16(l + j * 1024, g + j * 1024);
  };

  issue(0);
  for (int st = 0; st < NSTAGES; ++st) {
    __syncthreads();                       // buf[st&1] staged; buf[(st+1)&1] free
    if (st + 1 < NSTAGES) issue(st + 1);
    const char* buf = lds + (st & 1) * 16384;
#pragma unroll
    for (int kcL = 0; kcL < 2; ++kcL) {
      const int kc = (st & 3) * 2 + kcL;
#pragma unroll
      for (int ct = 0; ct < 8; ++ct) {
        // B[n=lane&15][k contiguous 8]; row r=ct*16+l16, granule g=kcL*4+quad,
        // stored at g' = g ^ (r&7)  -> 2-way-max bank aliasing (free)
        const int gp = (kcL * 4 + quad) ^ (l16 & 7);
        union { uint4 u; bf16x8 v; } cv;
        cv.u = *(const uint4*)(buf + (ct * 16 + l16) * 128 + gp * 16);
        acc[0][ct] = __builtin_amdgcn_mfma_f32_16x16x32_bf16(afrag[0][kc], cv.v, acc[0][ct], 0, 0, 0);
        acc[1][ct] = __builtin_amdgcn_mfma_f32_16x16x32_bf16(afrag[1][kc], cv.v, acc[1][ct], 0, 0, 0);
      }
    }
    if ((st & 3) == 3) {  // epilogue for finished 128-col tile: C/D row=quad*4+reg, col=l16
      const int nb = nbase0 + (st >> 2) * BN;
#pragma unroll
      for (int ct = 0; ct < 8; ++ct) {
        const float wv = w[nb + ct * 16 + l16];
#pragma unroll
        for (int rt = 0; rt < 2; ++rt) {
          f32x4 a = acc[rt][ct];
          outacc[rt][0] += wv * __builtin_amdgcn_exp2f(a[0]);
          outacc[rt][1] += wv * __builtin_amdgcn_exp2f(a[1]);
          outacc[rt][2] += wv * __builtin_amdgcn_exp2f(a[2]);
          outacc[rt][3] += wv * __builtin_amdgcn_exp2f(a[3]);
          acc[rt][ct] = fzero;
        }
      }
    }
  }

  // reduce over the 16 columns held across l16 within each quad, then atomic per row
#pragma unroll
  for (int rt = 0; rt < 2; ++rt)
#pragma unroll
    for (int i = 0; i < 4; ++i) {
      float v = outacc[rt][i];
      v += __shfl_xor(v, 1, 64);
      v += __shfl_xor(v, 2, 64);
      v += __shfl_xor(v, 4, 64);
      v += __shfl_xor(v, 8, 64);
      if (l16 == 0) {
        const int row = mblk + wave * 32 + rt * 16 + quad * 4 + i;
        atomicAdd(out + row, ea[row] * v);
      }
    }
}

extern "C" void kernel_launch(void* const* d_in, const int* in_sizes, int n_in,
                              void* d_out, int out_size, void* d_ws, size_t ws_size,
                              hipStream_t stream) {
  const float* Xq    = (const float*)d_in[0];
  const float* Xt    = (const float*)d_in[1];
  const float* alpha = (const float*)d_in[2];
  float* out = (float*)d_out;
  char*  ws  = (char*)d_ws;

  unsigned short* Aq = (unsigned short*)(ws + A_OFF);
  char*  Bst = ws + B_OFF;
  float* w   = (float*)(ws + W_OFF);
  float* ea  = (float*)(ws + EA_OFF);

  hipLaunchKernelGGL(prep_kernel, dim3((MM + NN) / 4), dim3(256), 0, stream,
                     Xq, Xt, alpha, out, Aq, Bst, w, ea);
  hipLaunchKernelGGL(rbf_main, dim3(NSPLIT, MM / BM), dim3(256), 0, stream,
                     Aq, Bst, w, ea, out);
}